// Round 2
// baseline (1359.905 us; speedup 1.0000x reference)
//
#include <hip/hip_runtime.h>
#include <hip/hip_bf16.h>

typedef unsigned short u16;
typedef unsigned int u32;
typedef __attribute__((ext_vector_type(8))) short bfrag8;
typedef __attribute__((ext_vector_type(4))) float f32x4;

#define ME_N 327660
#define MEMB_N 256
#define H1_N 512
#define H2_N 64
#define EEMB_N 256
#define LN_EPS 1e-5f

static __device__ __forceinline__ u16 f2bf(float f) {
  __hip_bfloat16 h = __float2bfloat16(f);
  return *reinterpret_cast<u16*>(&h);
}
static __device__ __forceinline__ float bf2f(u16 u) {
  union { u32 i; float f; } x; x.i = ((u32)u) << 16; return x.f;
}
static __device__ __forceinline__ u32 pack2(float a, float b) {
  return (u32)f2bf(a) | ((u32)f2bf(b) << 16);
}
static __device__ __forceinline__ float silu_f(float x) {
  return x / (1.0f + __expf(-x));
}

// ---- int32 -> float32 value conversion (harness reads whole out buf as f32) ----
__global__ void i2f_kernel(const int* __restrict__ src, float* __restrict__ dst, int n) {
  int i = blockIdx.x * 256 + threadIdx.x;
  if (i < n) dst[i] = (float)src[i];
}

// ---- weight transpose + bf16 convert: dst[n*K+k] = bf16(src[k*N+n]) ----
__global__ void wconv_kernel(const float* __restrict__ src, u16* __restrict__ dst,
                             int K, int N) {
  int i = blockIdx.x * 256 + threadIdx.x;
  if (i >= K * N) return;
  int n = i / K;
  int k = i - n * K;
  dst[i] = f2bf(src[(size_t)k * N + n]);
}

// ---- GEMM1: [ME,768](gathered) x [768,512] -> silu -> h1 bf16 ----
__launch_bounds__(256)
__global__ void gemm1_kernel(const float* __restrict__ mx, const int* __restrict__ me_i,
                             const float* __restrict__ me_x, const u16* __restrict__ w1t,
                             const float* __restrict__ b1, u16* __restrict__ h1) {
  __shared__ u16 Alds[128 * 40];
  __shared__ u16 Blds[128 * 40];
  const int t = threadIdx.x;
  const int m0 = blockIdx.x * 128;
  const int n0 = blockIdx.y * 128;
  const int r = t >> 1, sub = t & 1;
  int m_g = m0 + r; if (m_g > ME_N - 1) m_g = ME_N - 1;
  const float* rp = mx + (size_t)me_i[m_g] * MEMB_N;
  const float* cp = mx + (size_t)me_i[ME_N + m_g] * MEMB_N;
  const float* ep = me_x + (size_t)m_g * EEMB_N;
  const u16* bsrc = w1t + (size_t)(n0 + r) * 768;

  const int lane = t & 63;
  const int wid = t >> 6;
  const int wm = (wid >> 1) * 64;
  const int wn = (wid & 1) * 64;
  const int l16 = lane & 15;
  const int lk = (lane >> 4) * 8;

  f32x4 zero = {0.f, 0.f, 0.f, 0.f};
  f32x4 acc[4][4];
#pragma unroll
  for (int i = 0; i < 4; ++i)
#pragma unroll
    for (int j = 0; j < 4; ++j) acc[i][j] = zero;

  for (int kc = 0; kc < 24; ++kc) {
    const int third = kc >> 3;
    const float* p = (third == 0 ? rp : (third == 1 ? cp : ep)) + ((kc & 7) * 32 + sub * 16);
    const float4* p4 = reinterpret_cast<const float4*>(p);
    float4 v0 = p4[0], v1 = p4[1], v2 = p4[2], v3 = p4[3];
    const uint4* bp = reinterpret_cast<const uint4*>(bsrc + kc * 32 + sub * 16);
    uint4 bq0 = bp[0], bq1 = bp[1];
    uint4 q0, q1;
    q0.x = pack2(v0.x, v0.y); q0.y = pack2(v0.z, v0.w);
    q0.z = pack2(v1.x, v1.y); q0.w = pack2(v1.z, v1.w);
    q1.x = pack2(v2.x, v2.y); q1.y = pack2(v2.z, v2.w);
    q1.z = pack2(v3.x, v3.y); q1.w = pack2(v3.z, v3.w);
    *reinterpret_cast<uint4*>(&Alds[r * 40 + sub * 16]) = q0;
    *reinterpret_cast<uint4*>(&Alds[r * 40 + sub * 16 + 8]) = q1;
    *reinterpret_cast<uint4*>(&Blds[r * 40 + sub * 16]) = bq0;
    *reinterpret_cast<uint4*>(&Blds[r * 40 + sub * 16 + 8]) = bq1;
    __syncthreads();
    bfrag8 a[4], b[4];
#pragma unroll
    for (int i = 0; i < 4; ++i)
      a[i] = *reinterpret_cast<const bfrag8*>(&Alds[(wm + i * 16 + l16) * 40 + lk]);
#pragma unroll
    for (int i = 0; i < 4; ++i)
      b[i] = *reinterpret_cast<const bfrag8*>(&Blds[(wn + i * 16 + l16) * 40 + lk]);
#pragma unroll
    for (int i = 0; i < 4; ++i)
#pragma unroll
      for (int j = 0; j < 4; ++j)
        acc[i][j] = __builtin_amdgcn_mfma_f32_16x16x32_bf16(a[i], b[j], acc[i][j], 0, 0, 0);
    __syncthreads();
  }

  float bv[4];
#pragma unroll
  for (int j = 0; j < 4; ++j) bv[j] = b1[n0 + wn + j * 16 + l16];
  const int mr = wm + (lane >> 4) * 4;
#pragma unroll
  for (int i = 0; i < 4; ++i) {
#pragma unroll
    for (int rg = 0; rg < 4; ++rg) {
      int m = m0 + mr + i * 16 + rg;
      if (m < ME_N) {
#pragma unroll
        for (int j = 0; j < 4; ++j) {
          float v = silu_f(acc[i][j][rg] + bv[j]);
          h1[(size_t)m * H1_N + (n0 + wn + j * 16 + l16)] = f2bf(v);
        }
      }
    }
  }
}

// ---- GEMM2: h1[ME,512] x [512,64] -> silu -> h2 bf16 ----
__launch_bounds__(256)
__global__ void gemm2_kernel(const u16* __restrict__ h1, const u16* __restrict__ w2t,
                             const float* __restrict__ b2, u16* __restrict__ h2) {
  __shared__ u16 Alds[128 * 40];
  __shared__ u16 Blds[64 * 40];
  const int t = threadIdx.x;
  const int m0 = blockIdx.x * 128;
  const int r = t >> 1, sub = t & 1;
  int m_g = m0 + r; if (m_g > ME_N - 1) m_g = ME_N - 1;
  const u16* asrc = h1 + (size_t)m_g * H1_N;
  const u16* bsrc = w2t + (size_t)r * H1_N;  // deref only when t < 128 (r < 64)

  const int lane = t & 63;
  const int wid = t >> 6;
  const int l16 = lane & 15;
  const int lk = (lane >> 4) * 8;

  f32x4 zero = {0.f, 0.f, 0.f, 0.f};
  f32x4 acc[2][4];
#pragma unroll
  for (int i = 0; i < 2; ++i)
#pragma unroll
    for (int j = 0; j < 4; ++j) acc[i][j] = zero;

  for (int kc = 0; kc < 16; ++kc) {
    const uint4* ap = reinterpret_cast<const uint4*>(asrc + kc * 32 + sub * 16);
    uint4 a0 = ap[0], a1 = ap[1];
    *reinterpret_cast<uint4*>(&Alds[r * 40 + sub * 16]) = a0;
    *reinterpret_cast<uint4*>(&Alds[r * 40 + sub * 16 + 8]) = a1;
    if (t < 128) {
      const uint4* bp = reinterpret_cast<const uint4*>(bsrc + kc * 32 + sub * 16);
      uint4 b0 = bp[0], b1q = bp[1];
      *reinterpret_cast<uint4*>(&Blds[r * 40 + sub * 16]) = b0;
      *reinterpret_cast<uint4*>(&Blds[r * 40 + sub * 16 + 8]) = b1q;
    }
    __syncthreads();
    bfrag8 a[2], b[4];
#pragma unroll
    for (int i = 0; i < 2; ++i)
      a[i] = *reinterpret_cast<const bfrag8*>(&Alds[(wid * 32 + i * 16 + l16) * 40 + lk]);
#pragma unroll
    for (int j = 0; j < 4; ++j)
      b[j] = *reinterpret_cast<const bfrag8*>(&Blds[(j * 16 + l16) * 40 + lk]);
#pragma unroll
    for (int i = 0; i < 2; ++i)
#pragma unroll
      for (int j = 0; j < 4; ++j)
        acc[i][j] = __builtin_amdgcn_mfma_f32_16x16x32_bf16(a[i], b[j], acc[i][j], 0, 0, 0);
    __syncthreads();
  }

  float bv[4];
#pragma unroll
  for (int j = 0; j < 4; ++j) bv[j] = b2[j * 16 + l16];
#pragma unroll
  for (int i = 0; i < 2; ++i) {
#pragma unroll
    for (int rg = 0; rg < 4; ++rg) {
      int m = m0 + wid * 32 + i * 16 + (lane >> 4) * 4 + rg;
      if (m < ME_N) {
#pragma unroll
        for (int j = 0; j < 4; ++j) {
          float v = silu_f(acc[i][j][rg] + bv[j]);
          h2[(size_t)m * H2_N + (j * 16 + l16)] = f2bf(v);
        }
      }
    }
  }
}

// ---- GEMM3: h2[ME,64] x [64,256] -> h3 bf16 + block partial sums ----
__launch_bounds__(256)
__global__ void gemm3_kernel(const u16* __restrict__ h2, const u16* __restrict__ w3t,
                             const float* __restrict__ b3, u16* __restrict__ h3,
                             float* __restrict__ partials) {
  __shared__ u16 Alds[128 * 40];
  __shared__ u16 Blds[128 * 40];
  __shared__ float red[8];
  const int t = threadIdx.x;
  const int m0 = blockIdx.x * 128;
  const int n0 = blockIdx.y * 128;
  const int r = t >> 1, sub = t & 1;
  int m_g = m0 + r; if (m_g > ME_N - 1) m_g = ME_N - 1;
  const u16* asrc = h2 + (size_t)m_g * H2_N;
  const u16* bsrc = w3t + (size_t)(n0 + r) * H2_N;

  const int lane = t & 63;
  const int wid = t >> 6;
  const int wm = (wid >> 1) * 64;
  const int wn = (wid & 1) * 64;
  const int l16 = lane & 15;
  const int lk = (lane >> 4) * 8;

  f32x4 zero = {0.f, 0.f, 0.f, 0.f};
  f32x4 acc[4][4];
#pragma unroll
  for (int i = 0; i < 4; ++i)
#pragma unroll
    for (int j = 0; j < 4; ++j) acc[i][j] = zero;

  for (int kc = 0; kc < 2; ++kc) {
    const uint4* ap = reinterpret_cast<const uint4*>(asrc + kc * 32 + sub * 16);
    uint4 a0 = ap[0], a1 = ap[1];
    const uint4* bp = reinterpret_cast<const uint4*>(bsrc + kc * 32 + sub * 16);
    uint4 b0 = bp[0], b1q = bp[1];
    *reinterpret_cast<uint4*>(&Alds[r * 40 + sub * 16]) = a0;
    *reinterpret_cast<uint4*>(&Alds[r * 40 + sub * 16 + 8]) = a1;
    *reinterpret_cast<uint4*>(&Blds[r * 40 + sub * 16]) = b0;
    *reinterpret_cast<uint4*>(&Blds[r * 40 + sub * 16 + 8]) = b1q;
    __syncthreads();
    bfrag8 a[4], b[4];
#pragma unroll
    for (int i = 0; i < 4; ++i)
      a[i] = *reinterpret_cast<const bfrag8*>(&Alds[(wm + i * 16 + l16) * 40 + lk]);
#pragma unroll
    for (int i = 0; i < 4; ++i)
      b[i] = *reinterpret_cast<const bfrag8*>(&Blds[(wn + i * 16 + l16) * 40 + lk]);
#pragma unroll
    for (int i = 0; i < 4; ++i)
#pragma unroll
      for (int j = 0; j < 4; ++j)
        acc[i][j] = __builtin_amdgcn_mfma_f32_16x16x32_bf16(a[i], b[j], acc[i][j], 0, 0, 0);
    __syncthreads();
  }

  float bv[4];
#pragma unroll
  for (int j = 0; j < 4; ++j) bv[j] = b3[n0 + wn + j * 16 + l16];
  const int mr = wm + (lane >> 4) * 4;
  float lsum = 0.f, lsq = 0.f;
#pragma unroll
  for (int i = 0; i < 4; ++i) {
#pragma unroll
    for (int rg = 0; rg < 4; ++rg) {
      int m = m0 + mr + i * 16 + rg;
      if (m < ME_N) {
#pragma unroll
        for (int j = 0; j < 4; ++j) {
          float v = acc[i][j][rg] + bv[j];
          h3[(size_t)m * EEMB_N + (n0 + wn + j * 16 + l16)] = f2bf(v);
          lsum += v;
          lsq += v * v;
        }
      }
    }
  }
#pragma unroll
  for (int o = 32; o > 0; o >>= 1) {
    lsum += __shfl_down(lsum, o, 64);
    lsq  += __shfl_down(lsq, o, 64);
  }
  if (lane == 0) { red[wid] = lsum; red[4 + wid] = lsq; }
  __syncthreads();
  if (t == 0) {
    int bid = blockIdx.y * gridDim.x + blockIdx.x;
    partials[2 * bid]     = red[0] + red[1] + red[2] + red[3];
    partials[2 * bid + 1] = red[4] + red[5] + red[6] + red[7];
  }
}

// ---- deterministic two-stage stats reduce ----
__global__ void reduce_kernel(const float* __restrict__ partials, int n,
                              float* __restrict__ stats) {
  __shared__ float s1[256], s2[256];
  float a = 0.f, b = 0.f;
  for (int i = threadIdx.x; i < n; i += 256) { a += partials[2 * i]; b += partials[2 * i + 1]; }
  s1[threadIdx.x] = a; s2[threadIdx.x] = b;
  __syncthreads();
  for (int off = 128; off > 0; off >>= 1) {
    if ((int)threadIdx.x < off) {
      s1[threadIdx.x] += s1[threadIdx.x + off];
      s2[threadIdx.x] += s2[threadIdx.x + off];
    }
    __syncthreads();
  }
  if (threadIdx.x == 0) {
    double cnt = (double)ME_N * (double)EEMB_N;
    double mean = (double)s1[0] / cnt;
    double var = (double)s2[0] / cnt - mean * mean;
    stats[0] = (float)mean;
    stats[1] = (float)(1.0 / sqrt(var + (double)LN_EPS));
  }
}

// ---- final: me_x + (h3-mean)*rstd*ln_w + ln_b ----
__launch_bounds__(256)
__global__ void final_kernel(const u16* __restrict__ h3, const float* __restrict__ me_x,
                             const float* __restrict__ ln_w, const float* __restrict__ ln_b,
                             const float* __restrict__ stats, float* __restrict__ out) {
  const size_t total = (size_t)ME_N * EEMB_N;
  size_t i = ((size_t)blockIdx.x * 256 + threadIdx.x) * 8;
  if (i >= total) return;
  const float mean = stats[0], inv = stats[1];
  uint4 hv = *reinterpret_cast<const uint4*>(h3 + i);
  float h[8];
  h[0] = bf2f((u16)(hv.x & 0xffff)); h[1] = bf2f((u16)(hv.x >> 16));
  h[2] = bf2f((u16)(hv.y & 0xffff)); h[3] = bf2f((u16)(hv.y >> 16));
  h[4] = bf2f((u16)(hv.z & 0xffff)); h[5] = bf2f((u16)(hv.z >> 16));
  h[6] = bf2f((u16)(hv.w & 0xffff)); h[7] = bf2f((u16)(hv.w >> 16));
  float4 m0 = reinterpret_cast<const float4*>(me_x + i)[0];
  float4 m1 = reinterpret_cast<const float4*>(me_x + i)[1];
  float4 w0 = reinterpret_cast<const float4*>(ln_w + i)[0];
  float4 w1 = reinterpret_cast<const float4*>(ln_w + i)[1];
  float4 c0 = reinterpret_cast<const float4*>(ln_b + i)[0];
  float4 c1 = reinterpret_cast<const float4*>(ln_b + i)[1];
  float4 o0, o1;
  o0.x = m0.x + (h[0] - mean) * inv * w0.x + c0.x;
  o0.y = m0.y + (h[1] - mean) * inv * w0.y + c0.y;
  o0.z = m0.z + (h[2] - mean) * inv * w0.z + c0.z;
  o0.w = m0.w + (h[3] - mean) * inv * w0.w + c0.w;
  o1.x = m1.x + (h[4] - mean) * inv * w1.x + c1.x;
  o1.y = m1.y + (h[5] - mean) * inv * w1.y + c1.y;
  o1.z = m1.z + (h[6] - mean) * inv * w1.z + c1.z;
  o1.w = m1.w + (h[7] - mean) * inv * w1.w + c1.w;
  reinterpret_cast<float4*>(out + i)[0] = o0;
  reinterpret_cast<float4*>(out + i)[1] = o1;
}

extern "C" void kernel_launch(void* const* d_in, const int* in_sizes, int n_in,
                              void* d_out, int out_size, void* d_ws, size_t ws_size,
                              hipStream_t stream) {
  const float* mx   = (const float*)d_in[1];
  const int*   me_i = (const int*)d_in[2];
  const float* me_x = (const float*)d_in[3];
  const float* W1 = (const float*)d_in[8];
  const float* b1 = (const float*)d_in[9];
  const float* W2 = (const float*)d_in[10];
  const float* b2 = (const float*)d_in[11];
  const float* W3 = (const float*)d_in[12];
  const float* b3 = (const float*)d_in[13];
  const float* ln_w = (const float*)d_in[14];
  const float* ln_b = (const float*)d_in[15];

  // workspace layout (bytes, 256-aligned)
  char* ws = (char*)d_ws;
  u16* w1t = (u16*)(ws + 0);                       // 512*768*2  = 786432
  u16* w2t = (u16*)(ws + 786432);                  // 64*512*2   = 65536
  u16* w3t = (u16*)(ws + 786432 + 65536);          // 256*64*2   = 32768
  u16* h1  = (u16*)(ws + 884736);                  // ME*512*2   = 335523840
  u16* h2  = (u16*)(ws + 884736 + 335523840);      // ME*64*2    = 41940480
  u16* h3  = (u16*)(ws + 884736 + 335523840 + 41940480);            // ME*256*2 = 167761920
  float* partials = (float*)(ws + 884736 + 335523840 + 41940480 + 167761920);  // 5120*2*4
  float* stats    = (float*)(ws + 884736 + 335523840 + 41940480 + 167761920 + 40960);

  // output offsets: tuple order == input order, slot 3 replaced by me_x_new
  size_t off[8]; size_t a = 0;
  for (int i = 0; i < 8; ++i) { off[i] = a; a += (size_t)in_sizes[i]; }

  // pass-through: float arrays raw-copied; int index arrays converted to f32 VALUES
  for (int i = 0; i < 8; ++i) {
    if (i == 3) continue;
    if (i == 2 || i == 4 || i == 6) {
      int n = in_sizes[i];
      i2f_kernel<<<(n + 255) / 256, 256, 0, stream>>>(
          (const int*)d_in[i], (float*)d_out + off[i], n);
    } else {
      hipMemcpyAsync((char*)d_out + off[i] * 4, d_in[i], (size_t)in_sizes[i] * 4,
                     hipMemcpyDeviceToDevice, stream);
    }
  }

  // weights -> bf16 transposed [N][K]
  wconv_kernel<<<(768 * 512 + 255) / 256, 256, 0, stream>>>(W1, w1t, 768, 512);
  wconv_kernel<<<(512 * 64 + 255) / 256, 256, 0, stream>>>(W2, w2t, 512, 64);
  wconv_kernel<<<(64 * 256 + 255) / 256, 256, 0, stream>>>(W3, w3t, 64, 256);

  const int mtiles = (ME_N + 127) / 128;  // 2560
  gemm1_kernel<<<dim3(mtiles, 4), 256, 0, stream>>>(mx, me_i, me_x, w1t, b1, h1);
  gemm2_kernel<<<dim3(mtiles, 1), 256, 0, stream>>>(h1, w2t, b2, h2);
  gemm3_kernel<<<dim3(mtiles, 2), 256, 0, stream>>>(h2, w3t, b3, h3, partials);
  reduce_kernel<<<1, 256, 0, stream>>>(partials, mtiles * 2, stats);

  const size_t total8 = (size_t)ME_N * EEMB_N / 8;
  final_kernel<<<(int)((total8 + 255) / 256), 256, 0, stream>>>(
      h3, me_x, ln_w, ln_b, stats, (float*)d_out + off[3]);
}

// Round 3
// 974.365 us; speedup vs baseline: 1.3957x; 1.3957x over previous
//
#include <hip/hip_runtime.h>
#include <hip/hip_bf16.h>

typedef unsigned short u16;
typedef unsigned int u32;
typedef __attribute__((ext_vector_type(8))) short bfrag8;
typedef __attribute__((ext_vector_type(4))) float f32x4;

#define ME_N 327660
#define MEMB_N 256
#define H1_N 512
#define H2_N 64
#define EEMB_N 256
#define LN_EPS 1e-5f
#define NBLK 5120  // ceil(ME/64)

static __device__ __forceinline__ u16 f2bf(float f) {
  __hip_bfloat16 h = __float2bfloat16(f);
  return *reinterpret_cast<u16*>(&h);
}
static __device__ __forceinline__ float bf2f(u16 u) {
  union { u32 i; float f; } x; x.i = ((u32)u) << 16; return x.f;
}
static __device__ __forceinline__ u32 pack2(float a, float b) {
  return (u32)f2bf(a) | ((u32)f2bf(b) << 16);
}
static __device__ __forceinline__ float silu_f(float x) {
  return x / (1.0f + __expf(-x));
}
static __device__ __forceinline__ void gload_lds16(const void* g, void* l) {
  __builtin_amdgcn_global_load_lds(
      (const __attribute__((address_space(1))) void*)g,
      (__attribute__((address_space(3))) void*)l, 16, 0, 0);
}

// ---- int32 -> float32 value conversion (harness reads whole out buf as f32) ----
__global__ void i2f_kernel(const int* __restrict__ src, float* __restrict__ dst, int n) {
  int i = blockIdx.x * 256 + threadIdx.x;
  if (i < n) dst[i] = (float)src[i];
}

// ---- weight transpose + bf16 convert: dst[n*K+k] = bf16(src[k*N+n]) ----
__global__ void wconv_kernel(const float* __restrict__ src, u16* __restrict__ dst,
                             int K, int N) {
  int i = blockIdx.x * 256 + threadIdx.x;
  if (i >= K * N) return;
  int n = i / K;
  int k = i - n * K;
  dst[i] = f2bf(src[(size_t)k * N + n]);
}

// ---- fused: gather -> L1(768->512,silu) -> L2(512->64,silu) -> L3(64->256)+bias
//      one block = 64 edge rows, full N; h1/h2 never leave the CU.
__launch_bounds__(256, 2)
__global__ void gemm_fused_kernel(const float* __restrict__ mx, const int* __restrict__ me_i,
                                  const float* __restrict__ me_x,
                                  const u16* __restrict__ w1t, const float* __restrict__ b1,
                                  const u16* __restrict__ w2t, const float* __restrict__ b2,
                                  const u16* __restrict__ w3t, const float* __restrict__ b3,
                                  u16* __restrict__ h3, float* __restrict__ partials) {
  // Alds: main-loop A tile [64][72] (pad 8 -> conflict-free) ; later h2T [64][72]
  // Blds: main-loop B tile [512][64] linear (global_load_lds) ; later h1T [64][520]
  __shared__ u16 Alds[64 * 72];
  __shared__ u16 Blds[64 * 520];
  __shared__ float red[8];

  const int t = threadIdx.x;
  const int m0 = blockIdx.x * 64;
  const int lane = t & 63;
  const int wid = t >> 6;
  const int l16 = lane & 15;
  const int k4 = lane >> 4;

  // A-gather mapping: thread t stages row t>>2, 16-col chunk (t&3)*16
  const int arow = t >> 2;
  const int acol = (t & 3) * 16;
  int m_g = m0 + arow; if (m_g > ME_N - 1) m_g = ME_N - 1;
  const float* rp = mx + (size_t)me_i[m_g] * MEMB_N;
  const float* cp = mx + (size_t)me_i[ME_N + m_g] * MEMB_N;
  const float* ep = me_x + (size_t)m_g * EEMB_N;

  const f32x4 zero = {0.f, 0.f, 0.f, 0.f};
  f32x4 acc[4][8];
#pragma unroll
  for (int i = 0; i < 4; ++i)
#pragma unroll
    for (int j = 0; j < 8; ++j) acc[i][j] = zero;

  // ================= main loop: h1_acc = gather(A) @ W1 =================
  for (int kc = 0; kc < 12; ++kc) {
    // issue B stage first (async DMA to LDS), then A loads, then pack/ds_write
    const u16* bsrc = w1t + kc * 64 + (lane & 7) * 8;
#pragma unroll
    for (int q = 0; q < 16; ++q) {
      const int nbase = wid * 128 + q * 8;
      gload_lds16(bsrc + (size_t)(nbase + (lane >> 3)) * 768, &Blds[nbase * 64]);
    }
    const float* p = (kc < 4 ? rp : (kc < 8 ? cp : ep)) + ((kc & 3) * 64 + acol);
    const float4* p4 = reinterpret_cast<const float4*>(p);
    float4 v0 = p4[0], v1 = p4[1], v2 = p4[2], v3 = p4[3];
    uint4 q0, q1;
    q0.x = pack2(v0.x, v0.y); q0.y = pack2(v0.z, v0.w);
    q0.z = pack2(v1.x, v1.y); q0.w = pack2(v1.z, v1.w);
    q1.x = pack2(v2.x, v2.y); q1.y = pack2(v2.z, v2.w);
    q1.z = pack2(v3.x, v3.y); q1.w = pack2(v3.z, v3.w);
    *reinterpret_cast<uint4*>(&Alds[arow * 72 + acol]) = q0;
    *reinterpret_cast<uint4*>(&Alds[arow * 72 + acol + 8]) = q1;
    __syncthreads();
#pragma unroll
    for (int ks = 0; ks < 2; ++ks) {
      bfrag8 a[4], b[8];
#pragma unroll
      for (int i = 0; i < 4; ++i)
        a[i] = *reinterpret_cast<const bfrag8*>(&Alds[(i * 16 + l16) * 72 + ks * 32 + k4 * 8]);
#pragma unroll
      for (int j = 0; j < 8; ++j)
        b[j] = *reinterpret_cast<const bfrag8*>(&Blds[(wid * 128 + j * 16 + l16) * 64 + ks * 32 + k4 * 8]);
#pragma unroll
      for (int i = 0; i < 4; ++i)
#pragma unroll
        for (int j = 0; j < 8; ++j)
          acc[i][j] = __builtin_amdgcn_mfma_f32_16x16x32_bf16(a[i], b[j], acc[i][j], 0, 0, 0);
    }
    __syncthreads();
  }

  // ============ phase 1: h1 = silu(acc + b1) -> h1T LDS [64][520] ============
  float b1v[8];
#pragma unroll
  for (int j = 0; j < 8; ++j) b1v[j] = b1[wid * 128 + j * 16 + l16];
#pragma unroll
  for (int i = 0; i < 4; ++i)
#pragma unroll
    for (int j = 0; j < 8; ++j)
#pragma unroll
      for (int rg = 0; rg < 4; ++rg) {
        float v = silu_f(acc[i][j][rg] + b1v[j]);
        Blds[(i * 16 + k4 * 4 + rg) * 520 + wid * 128 + j * 16 + l16] = f2bf(v);
      }
  __syncthreads();

  // ============ phase 2: h2 = silu(h1T @ W2 + b2) -> h2T LDS [64][72] ============
  const int n2 = wid * 16 + l16;  // this wave's 16 output cols of layer 2
  bfrag8 w2f[16];
#pragma unroll
  for (int ks = 0; ks < 16; ++ks)
    w2f[ks] = *reinterpret_cast<const bfrag8*>(w2t + (size_t)n2 * 512 + ks * 32 + k4 * 8);
  f32x4 acc2[4];
#pragma unroll
  for (int i = 0; i < 4; ++i) acc2[i] = zero;
#pragma unroll
  for (int ks = 0; ks < 16; ++ks) {
#pragma unroll
    for (int i = 0; i < 4; ++i) {
      bfrag8 a2 = *reinterpret_cast<const bfrag8*>(&Blds[(i * 16 + l16) * 520 + ks * 32 + k4 * 8]);
      acc2[i] = __builtin_amdgcn_mfma_f32_16x16x32_bf16(a2, w2f[ks], acc2[i], 0, 0, 0);
    }
  }
  const float b2v = b2[n2];
#pragma unroll
  for (int i = 0; i < 4; ++i)
#pragma unroll
    for (int rg = 0; rg < 4; ++rg) {
      float v = silu_f(acc2[i][rg] + b2v);
      Alds[(i * 16 + k4 * 4 + rg) * 72 + n2] = f2bf(v);
    }
  __syncthreads();

  // ============ phase 3: h3 = h2T @ W3 + b3 ; write + LN partial sums ============
  bfrag8 w3f[4][2];
#pragma unroll
  for (int j = 0; j < 4; ++j)
#pragma unroll
    for (int ks = 0; ks < 2; ++ks)
      w3f[j][ks] = *reinterpret_cast<const bfrag8*>(
          w3t + (size_t)(wid * 64 + j * 16 + l16) * 64 + ks * 32 + k4 * 8);
  f32x4 acc3[4][4];
#pragma unroll
  for (int i = 0; i < 4; ++i)
#pragma unroll
    for (int j = 0; j < 4; ++j) acc3[i][j] = zero;
#pragma unroll
  for (int ks = 0; ks < 2; ++ks) {
    bfrag8 a3[4];
#pragma unroll
    for (int i = 0; i < 4; ++i)
      a3[i] = *reinterpret_cast<const bfrag8*>(&Alds[(i * 16 + l16) * 72 + ks * 32 + k4 * 8]);
#pragma unroll
    for (int i = 0; i < 4; ++i)
#pragma unroll
      for (int j = 0; j < 4; ++j)
        acc3[i][j] = __builtin_amdgcn_mfma_f32_16x16x32_bf16(a3[i], w3f[j][ks], acc3[i][j], 0, 0, 0);
  }

  float b3v[4];
#pragma unroll
  for (int j = 0; j < 4; ++j) b3v[j] = b3[wid * 64 + j * 16 + l16];
  float lsum = 0.f, lsq = 0.f;
#pragma unroll
  for (int i = 0; i < 4; ++i)
#pragma unroll
    for (int rg = 0; rg < 4; ++rg) {
      int m = m0 + i * 16 + k4 * 4 + rg;
      if (m < ME_N) {
#pragma unroll
        for (int j = 0; j < 4; ++j) {
          float v = acc3[i][j][rg] + b3v[j];
          h3[(size_t)m * EEMB_N + wid * 64 + j * 16 + l16] = f2bf(v);
          lsum += v;
          lsq += v * v;
        }
      }
    }
#pragma unroll
  for (int o = 32; o > 0; o >>= 1) {
    lsum += __shfl_down(lsum, o, 64);
    lsq  += __shfl_down(lsq, o, 64);
  }
  if (lane == 0) { red[wid] = lsum; red[4 + wid] = lsq; }
  __syncthreads();
  if (t == 0) {
    partials[2 * blockIdx.x]     = red[0] + red[1] + red[2] + red[3];
    partials[2 * blockIdx.x + 1] = red[4] + red[5] + red[6] + red[7];
  }
}

// ---- deterministic two-stage stats reduce ----
__global__ void reduce_kernel(const float* __restrict__ partials, int n,
                              float* __restrict__ stats) {
  __shared__ float s1[256], s2[256];
  float a = 0.f, b = 0.f;
  for (int i = threadIdx.x; i < n; i += 256) { a += partials[2 * i]; b += partials[2 * i + 1]; }
  s1[threadIdx.x] = a; s2[threadIdx.x] = b;
  __syncthreads();
  for (int off = 128; off > 0; off >>= 1) {
    if ((int)threadIdx.x < off) {
      s1[threadIdx.x] += s1[threadIdx.x + off];
      s2[threadIdx.x] += s2[threadIdx.x + off];
    }
    __syncthreads();
  }
  if (threadIdx.x == 0) {
    double cnt = (double)ME_N * (double)EEMB_N;
    double mean = (double)s1[0] / cnt;
    double var = (double)s2[0] / cnt - mean * mean;
    stats[0] = (float)mean;
    stats[1] = (float)(1.0 / sqrt(var + (double)LN_EPS));
  }
}

// ---- final: me_x + (h3-mean)*rstd*ln_w + ln_b ----
__launch_bounds__(256)
__global__ void final_kernel(const u16* __restrict__ h3, const float* __restrict__ me_x,
                             const float* __restrict__ ln_w, const float* __restrict__ ln_b,
                             const float* __restrict__ stats, float* __restrict__ out) {
  const size_t total = (size_t)ME_N * EEMB_N;
  size_t i = ((size_t)blockIdx.x * 256 + threadIdx.x) * 8;
  if (i >= total) return;
  const float mean = stats[0], inv = stats[1];
  uint4 hv = *reinterpret_cast<const uint4*>(h3 + i);
  float h[8];
  h[0] = bf2f((u16)(hv.x & 0xffff)); h[1] = bf2f((u16)(hv.x >> 16));
  h[2] = bf2f((u16)(hv.y & 0xffff)); h[3] = bf2f((u16)(hv.y >> 16));
  h[4] = bf2f((u16)(hv.z & 0xffff)); h[5] = bf2f((u16)(hv.z >> 16));
  h[6] = bf2f((u16)(hv.w & 0xffff)); h[7] = bf2f((u16)(hv.w >> 16));
  float4 m0 = reinterpret_cast<const float4*>(me_x + i)[0];
  float4 m1 = reinterpret_cast<const float4*>(me_x + i)[1];
  float4 w0 = reinterpret_cast<const float4*>(ln_w + i)[0];
  float4 w1 = reinterpret_cast<const float4*>(ln_w + i)[1];
  float4 c0 = reinterpret_cast<const float4*>(ln_b + i)[0];
  float4 c1 = reinterpret_cast<const float4*>(ln_b + i)[1];
  float4 o0, o1;
  o0.x = m0.x + (h[0] - mean) * inv * w0.x + c0.x;
  o0.y = m0.y + (h[1] - mean) * inv * w0.y + c0.y;
  o0.z = m0.z + (h[2] - mean) * inv * w0.z + c0.z;
  o0.w = m0.w + (h[3] - mean) * inv * w0.w + c0.w;
  o1.x = m1.x + (h[4] - mean) * inv * w1.x + c1.x;
  o1.y = m1.y + (h[5] - mean) * inv * w1.y + c1.y;
  o1.z = m1.z + (h[6] - mean) * inv * w1.z + c1.z;
  o1.w = m1.w + (h[7] - mean) * inv * w1.w + c1.w;
  reinterpret_cast<float4*>(out + i)[0] = o0;
  reinterpret_cast<float4*>(out + i)[1] = o1;
}

extern "C" void kernel_launch(void* const* d_in, const int* in_sizes, int n_in,
                              void* d_out, int out_size, void* d_ws, size_t ws_size,
                              hipStream_t stream) {
  const float* mx   = (const float*)d_in[1];
  const int*   me_i = (const int*)d_in[2];
  const float* me_x = (const float*)d_in[3];
  const float* W1 = (const float*)d_in[8];
  const float* b1 = (const float*)d_in[9];
  const float* W2 = (const float*)d_in[10];
  const float* b2 = (const float*)d_in[11];
  const float* W3 = (const float*)d_in[12];
  const float* b3 = (const float*)d_in[13];
  const float* ln_w = (const float*)d_in[14];
  const float* ln_b = (const float*)d_in[15];

  // workspace layout (bytes, 256-aligned)
  char* ws = (char*)d_ws;
  u16* w1t = (u16*)(ws + 0);          // [512][768] bf16 = 786432 B
  u16* w2t = (u16*)(ws + 786432);     // [64][512]  bf16 = 65536 B
  u16* w3t = (u16*)(ws + 851968);     // [256][64]  bf16 = 32768 B
  u16* h3  = (u16*)(ws + 884736);     // [ME][256]  bf16 = 167761920 B
  float* partials = (float*)(ws + 884736 + 167761920);          // NBLK*2*4 = 40960 B
  float* stats    = (float*)(ws + 884736 + 167761920 + 40960);  // 2 floats

  // output offsets: tuple order == input order, slot 3 replaced by me_x_new
  size_t off[8]; size_t a = 0;
  for (int i = 0; i < 8; ++i) { off[i] = a; a += (size_t)in_sizes[i]; }

  // pass-through: float arrays raw-copied; int index arrays converted to f32 VALUES
  for (int i = 0; i < 8; ++i) {
    if (i == 3) continue;
    if (i == 2 || i == 4 || i == 6) {
      int n = in_sizes[i];
      i2f_kernel<<<(n + 255) / 256, 256, 0, stream>>>(
          (const int*)d_in[i], (float*)d_out + off[i], n);
    } else {
      hipMemcpyAsync((char*)d_out + off[i] * 4, d_in[i], (size_t)in_sizes[i] * 4,
                     hipMemcpyDeviceToDevice, stream);
    }
  }

  // weights -> bf16 transposed [N][K]
  wconv_kernel<<<(768 * 512 + 255) / 256, 256, 0, stream>>>(W1, w1t, 768, 512);
  wconv_kernel<<<(512 * 64 + 255) / 256, 256, 0, stream>>>(W2, w2t, 512, 64);
  wconv_kernel<<<(64 * 256 + 255) / 256, 256, 0, stream>>>(W3, w3t, 64, 256);

  gemm_fused_kernel<<<NBLK, 256, 0, stream>>>(mx, me_i, me_x, w1t, b1, w2t, b2,
                                              w3t, b3, h3, partials);
  reduce_kernel<<<1, 256, 0, stream>>>(partials, NBLK, stats);

  const size_t total8 = (size_t)ME_N * EEMB_N / 8;
  final_kernel<<<(int)((total8 + 255) / 256), 256, 0, stream>>>(
      h3, me_x, ln_w, ln_b, stats, (float*)d_out + off[3]);
}

// Round 4
// 911.811 us; speedup vs baseline: 1.4914x; 1.0686x over previous
//
#include <hip/hip_runtime.h>
#include <hip/hip_bf16.h>

typedef unsigned short u16;
typedef unsigned int u32;
typedef __attribute__((ext_vector_type(8))) short bfrag8;
typedef __attribute__((ext_vector_type(4))) float f32x4;

#define ME_N 327660
#define MN_N 40962
#define MEMB_N 256
#define H1_N 512
#define H2_N 64
#define EEMB_N 256
#define LN_EPS 1e-5f
#define NBLK 5120  // ceil(ME/64)

static __device__ __forceinline__ u16 f2bf(float f) {
  __hip_bfloat16 h = __float2bfloat16(f);
  return *reinterpret_cast<u16*>(&h);
}
static __device__ __forceinline__ float bf2f(u16 u) {
  union { u32 i; float f; } x; x.i = ((u32)u) << 16; return x.f;
}
static __device__ __forceinline__ u32 pack2(float a, float b) {
  return (u32)f2bf(a) | ((u32)f2bf(b) << 16);
}
static __device__ __forceinline__ float silu_f(float x) {
  return x / (1.0f + __expf(-x));
}
static __device__ __forceinline__ void gload_lds16(const void* g, void* l) {
  __builtin_amdgcn_global_load_lds(
      (const __attribute__((address_space(1))) void*)g,
      (__attribute__((address_space(3))) void*)l, 16, 0, 0);
}

// ---- int32 -> float32 value conversion (harness reads whole out buf as f32) ----
__global__ void i2f_kernel(const int* __restrict__ src, float* __restrict__ dst, int n) {
  int i = blockIdx.x * 256 + threadIdx.x;
  if (i < n) dst[i] = (float)src[i];
}

// ---- mx fp32 -> bf16, straight copy, 8 elems/thread ----
__global__ void bfconv_kernel(const float* __restrict__ src, u16* __restrict__ dst, int n) {
  int i = (blockIdx.x * 256 + threadIdx.x) * 8;
  if (i >= n) return;
  float4 v0 = reinterpret_cast<const float4*>(src + i)[0];
  float4 v1 = reinterpret_cast<const float4*>(src + i)[1];
  uint4 q;
  q.x = pack2(v0.x, v0.y); q.y = pack2(v0.z, v0.w);
  q.z = pack2(v1.x, v1.y); q.w = pack2(v1.z, v1.w);
  *reinterpret_cast<uint4*>(dst + i) = q;
}

// ---- W1 -> fragment-contiguous bf16 layout [J=32][kc=12][ks=2][k4=4][l16=16][8]
//      element i holds W1[k][n], n=J*16+l16, k=kc*64+ks*32+k4*8+e
__global__ void wconv1_kernel(const float* __restrict__ src, u16* __restrict__ dst) {
  int i = blockIdx.x * 256 + threadIdx.x;
  if (i >= 512 * 768) return;
  int e   = i & 7;
  int l16 = (i >> 3) & 15;
  int k4  = (i >> 7) & 3;
  int ks  = (i >> 9) & 1;
  int rest = i >> 10;
  int kc = rest % 12;
  int J  = rest / 12;
  int n = J * 16 + l16;
  int k = kc * 64 + ks * 32 + k4 * 8 + e;
  dst[i] = f2bf(src[(size_t)k * 512 + n]);
}

// ---- generic weight transpose + bf16: dst[n*K+k] = src[k*N+n] ----
__global__ void wconv_kernel(const float* __restrict__ src, u16* __restrict__ dst,
                             int K, int N) {
  int i = blockIdx.x * 256 + threadIdx.x;
  if (i >= K * N) return;
  int n = i / K;
  int k = i - n * K;
  dst[i] = f2bf(src[(size_t)k * N + n]);
}

// ---- fused: gather -> L1(768->512,silu) -> L2(512->64,silu) -> L3(64->256)+bias
//      B(W1) from L2 to registers (no LDS); A via swizzled global_load_lds dbuf.
__launch_bounds__(256, 2)
__global__ void gemm_fused_kernel(const u16* __restrict__ mxb, const int* __restrict__ me_i,
                                  const float* __restrict__ me_x,
                                  const u16* __restrict__ w1f, const float* __restrict__ b1,
                                  const u16* __restrict__ w2t, const float* __restrict__ b2,
                                  const u16* __restrict__ w3t, const float* __restrict__ b3,
                                  u16* __restrict__ h3, float* __restrict__ partials) {
  // S aliases: main loop A dbuf 2x4096 u16 (16KB) ; then h1T [64][520] + h2T [64][72]
  __shared__ u16 S[64 * 520 + 64 * 72];
  __shared__ float red[8];
  u16* Abuf = S;
  u16* h1T  = S;
  u16* h2T  = S + 64 * 520;

  const int t = threadIdx.x;
  const int m0 = blockIdx.x * 64;
  const int lane = t & 63;
  const int wid = t >> 6;
  const int l16 = lane & 15;
  const int k4 = lane >> 4;

  // --- A-stage mapping (gload_lds path, kc<8): chunks c0=wid*128+lane, c1=c0+64
  const int c0 = wid * 128 + lane;
  const int c1 = c0 + 64;
  const int r0 = c0 >> 3, r1 = c1 >> 3;
  const int e0s = ((c0 & 7) ^ (r0 & 7)) * 8;  // swizzled elem offset in 64-elem row
  const int e1s = ((c1 & 7) ^ (r1 & 7)) * 8;
  const int mg0 = min(m0 + r0, ME_N - 1);
  const int mg1 = min(m0 + r1, ME_N - 1);
  const u16* row0r = mxb + (size_t)me_i[mg0] * MEMB_N;
  const u16* row0c = mxb + (size_t)me_i[ME_N + mg0] * MEMB_N;
  const u16* row1r = mxb + (size_t)me_i[mg1] * MEMB_N;
  const u16* row1c = mxb + (size_t)me_i[ME_N + mg1] * MEMB_N;
  // --- me_x pack path (kc>=8): thread -> row rr, 16-elem group g
  const int rr = t >> 2, g = t & 3;
  const float* pe = me_x + (size_t)min(m0 + rr, ME_N - 1) * EEMB_N;
  const int E0 = (g * 16) ^ ((rr & 7) * 8);
  const int E1 = (g * 16 + 8) ^ ((rr & 7) * 8);

  const f32x4 zero = {0.f, 0.f, 0.f, 0.f};
  f32x4 acc[4][8];
#pragma unroll
  for (int i = 0; i < 4; ++i)
#pragma unroll
    for (int j = 0; j < 8; ++j) acc[i][j] = zero;

  // stage A(kc) into Abuf[(kc&1)*4096]
  auto stage_A = [&](int kcn) {
    if (kcn < 8) {
      const u16* s0 = (kcn < 4 ? row0r : row0c) + ((kcn & 3) * 64 + e0s);
      const u16* s1 = (kcn < 4 ? row1r : row1c) + ((kcn & 3) * 64 + e1s);
      u16* lb = Abuf + (kcn & 1) * 4096 + wid * 1024;
      gload_lds16(s0, lb);
      gload_lds16(s1, lb + 512);
    } else {
      const float4* p4 = reinterpret_cast<const float4*>(pe + (kcn - 8) * 64 + g * 16);
      float4 v0 = p4[0], v1 = p4[1], v2 = p4[2], v3 = p4[3];
      uint4 qa, qb;
      qa.x = pack2(v0.x, v0.y); qa.y = pack2(v0.z, v0.w);
      qa.z = pack2(v1.x, v1.y); qa.w = pack2(v1.z, v1.w);
      qb.x = pack2(v2.x, v2.y); qb.y = pack2(v2.z, v2.w);
      qb.z = pack2(v3.x, v3.y); qb.w = pack2(v3.z, v3.w);
      u16* d = Abuf + (kcn & 1) * 4096 + rr * 64;
      *reinterpret_cast<uint4*>(d + E0) = qa;
      *reinterpret_cast<uint4*>(d + E1) = qb;
    }
  };

  stage_A(0);
  __syncthreads();

  // ================= main loop: acc = gather(A) @ W1 =================
  for (int kc = 0; kc < 12; ++kc) {
    if (kc < 11) stage_A(kc + 1);
    // B fragments: wave-private W1 panel, fragment-contiguous, from L2
    bfrag8 bfr[2][8];
    {
      const u16* bb = w1f + (size_t)kc * 1024 + k4 * 128 + l16 * 8;
      const size_t woff = (size_t)(wid * 8) * 12288;
#pragma unroll
      for (int ks = 0; ks < 2; ++ks)
#pragma unroll
        for (int j = 0; j < 8; ++j)
          bfr[ks][j] = *reinterpret_cast<const bfrag8*>(bb + woff + (size_t)j * 12288 + ks * 512);
    }
    const u16* ab = Abuf + (kc & 1) * 4096;
#pragma unroll
    for (int ks = 0; ks < 2; ++ks) {
      bfrag8 a[4];
#pragma unroll
      for (int i = 0; i < 4; ++i)
        a[i] = *reinterpret_cast<const bfrag8*>(
            &ab[(i * 16 + l16) * 64 + ((ks * 32 + k4 * 8) ^ ((l16 & 7) * 8))]);
#pragma unroll
      for (int i = 0; i < 4; ++i)
#pragma unroll
        for (int j = 0; j < 8; ++j)
          acc[i][j] = __builtin_amdgcn_mfma_f32_16x16x32_bf16(a[i], bfr[ks][j], acc[i][j], 0, 0, 0);
    }
    __syncthreads();
  }

  // ============ phase 1: h1 = silu(acc + b1) -> h1T LDS [64][520] ============
  float b1v[8];
#pragma unroll
  for (int j = 0; j < 8; ++j) b1v[j] = b1[wid * 128 + j * 16 + l16];
#pragma unroll
  for (int i = 0; i < 4; ++i)
#pragma unroll
    for (int j = 0; j < 8; ++j)
#pragma unroll
      for (int rg = 0; rg < 4; ++rg) {
        float v = silu_f(acc[i][j][rg] + b1v[j]);
        h1T[(i * 16 + k4 * 4 + rg) * 520 + wid * 128 + j * 16 + l16] = f2bf(v);
      }
  __syncthreads();

  // ============ phase 2: h2 = silu(h1T @ W2 + b2) -> h2T LDS [64][72] ============
  const int n2 = wid * 16 + l16;
  bfrag8 w2f[16];
#pragma unroll
  for (int ks = 0; ks < 16; ++ks)
    w2f[ks] = *reinterpret_cast<const bfrag8*>(w2t + (size_t)n2 * 512 + ks * 32 + k4 * 8);
  f32x4 acc2[4];
#pragma unroll
  for (int i = 0; i < 4; ++i) acc2[i] = zero;
#pragma unroll
  for (int ks = 0; ks < 16; ++ks) {
#pragma unroll
    for (int i = 0; i < 4; ++i) {
      bfrag8 a2 = *reinterpret_cast<const bfrag8*>(&h1T[(i * 16 + l16) * 520 + ks * 32 + k4 * 8]);
      acc2[i] = __builtin_amdgcn_mfma_f32_16x16x32_bf16(a2, w2f[ks], acc2[i], 0, 0, 0);
    }
  }
  const float b2v = b2[n2];
#pragma unroll
  for (int i = 0; i < 4; ++i)
#pragma unroll
    for (int rg = 0; rg < 4; ++rg) {
      float v = silu_f(acc2[i][rg] + b2v);
      h2T[(i * 16 + k4 * 4 + rg) * 72 + n2] = f2bf(v);
    }
  __syncthreads();

  // ============ phase 3: h3 = h2T @ W3 + b3 ; write + LN partial sums ============
  bfrag8 w3f[4][2];
#pragma unroll
  for (int j = 0; j < 4; ++j)
#pragma unroll
    for (int ks = 0; ks < 2; ++ks)
      w3f[j][ks] = *reinterpret_cast<const bfrag8*>(
          w3t + (size_t)(wid * 64 + j * 16 + l16) * 64 + ks * 32 + k4 * 8);
  f32x4 acc3[4][4];
#pragma unroll
  for (int i = 0; i < 4; ++i)
#pragma unroll
    for (int j = 0; j < 4; ++j) acc3[i][j] = zero;
#pragma unroll
  for (int ks = 0; ks < 2; ++ks) {
    bfrag8 a3[4];
#pragma unroll
    for (int i = 0; i < 4; ++i)
      a3[i] = *reinterpret_cast<const bfrag8*>(&h2T[(i * 16 + l16) * 72 + ks * 32 + k4 * 8]);
#pragma unroll
    for (int i = 0; i < 4; ++i)
#pragma unroll
      for (int j = 0; j < 4; ++j)
        acc3[i][j] = __builtin_amdgcn_mfma_f32_16x16x32_bf16(a3[i], w3f[j][ks], acc3[i][j], 0, 0, 0);
  }

  float b3v[4];
#pragma unroll
  for (int j = 0; j < 4; ++j) b3v[j] = b3[wid * 64 + j * 16 + l16];
  float lsum = 0.f, lsq = 0.f;
#pragma unroll
  for (int i = 0; i < 4; ++i)
#pragma unroll
    for (int rg = 0; rg < 4; ++rg) {
      int m = m0 + i * 16 + k4 * 4 + rg;
      if (m < ME_N) {
#pragma unroll
        for (int j = 0; j < 4; ++j) {
          float v = acc3[i][j][rg] + b3v[j];
          h3[(size_t)m * EEMB_N + wid * 64 + j * 16 + l16] = f2bf(v);
          lsum += v;
          lsq += v * v;
        }
      }
    }
#pragma unroll
  for (int o = 32; o > 0; o >>= 1) {
    lsum += __shfl_down(lsum, o, 64);
    lsq  += __shfl_down(lsq, o, 64);
  }
  if (lane == 0) { red[wid] = lsum; red[4 + wid] = lsq; }
  __syncthreads();
  if (t == 0) {
    partials[2 * blockIdx.x]     = red[0] + red[1] + red[2] + red[3];
    partials[2 * blockIdx.x + 1] = red[4] + red[5] + red[6] + red[7];
  }
}

// ---- deterministic two-stage stats reduce ----
__global__ void reduce_kernel(const float* __restrict__ partials, int n,
                              float* __restrict__ stats) {
  __shared__ float s1[256], s2[256];
  float a = 0.f, b = 0.f;
  for (int i = threadIdx.x; i < n; i += 256) { a += partials[2 * i]; b += partials[2 * i + 1]; }
  s1[threadIdx.x] = a; s2[threadIdx.x] = b;
  __syncthreads();
  for (int off = 128; off > 0; off >>= 1) {
    if ((int)threadIdx.x < off) {
      s1[threadIdx.x] += s1[threadIdx.x + off];
      s2[threadIdx.x] += s2[threadIdx.x + off];
    }
    __syncthreads();
  }
  if (threadIdx.x == 0) {
    double cnt = (double)ME_N * (double)EEMB_N;
    double mean = (double)s1[0] / cnt;
    double var = (double)s2[0] / cnt - mean * mean;
    stats[0] = (float)mean;
    stats[1] = (float)(1.0 / sqrt(var + (double)LN_EPS));
  }
}

// ---- final: me_x + (h3-mean)*rstd*ln_w + ln_b ----
__launch_bounds__(256)
__global__ void final_kernel(const u16* __restrict__ h3, const float* __restrict__ me_x,
                             const float* __restrict__ ln_w, const float* __restrict__ ln_b,
                             const float* __restrict__ stats, float* __restrict__ out) {
  const size_t total = (size_t)ME_N * EEMB_N;
  size_t i = ((size_t)blockIdx.x * 256 + threadIdx.x) * 8;
  if (i >= total) return;
  const float mean = stats[0], inv = stats[1];
  uint4 hv = *reinterpret_cast<const uint4*>(h3 + i);
  float h[8];
  h[0] = bf2f((u16)(hv.x & 0xffff)); h[1] = bf2f((u16)(hv.x >> 16));
  h[2] = bf2f((u16)(hv.y & 0xffff)); h[3] = bf2f((u16)(hv.y >> 16));
  h[4] = bf2f((u16)(hv.z & 0xffff)); h[5] = bf2f((u16)(hv.z >> 16));
  h[6] = bf2f((u16)(hv.w & 0xffff)); h[7] = bf2f((u16)(hv.w >> 16));
  float4 m0 = reinterpret_cast<const float4*>(me_x + i)[0];
  float4 m1 = reinterpret_cast<const float4*>(me_x + i)[1];
  float4 w0 = reinterpret_cast<const float4*>(ln_w + i)[0];
  float4 w1 = reinterpret_cast<const float4*>(ln_w + i)[1];
  float4 c0 = reinterpret_cast<const float4*>(ln_b + i)[0];
  float4 c1 = reinterpret_cast<const float4*>(ln_b + i)[1];
  float4 o0, o1;
  o0.x = m0.x + (h[0] - mean) * inv * w0.x + c0.x;
  o0.y = m0.y + (h[1] - mean) * inv * w0.y + c0.y;
  o0.z = m0.z + (h[2] - mean) * inv * w0.z + c0.z;
  o0.w = m0.w + (h[3] - mean) * inv * w0.w + c0.w;
  o1.x = m1.x + (h[4] - mean) * inv * w1.x + c1.x;
  o1.y = m1.y + (h[5] - mean) * inv * w1.y + c1.y;
  o1.z = m1.z + (h[6] - mean) * inv * w1.z + c1.z;
  o1.w = m1.w + (h[7] - mean) * inv * w1.w + c1.w;
  reinterpret_cast<float4*>(out + i)[0] = o0;
  reinterpret_cast<float4*>(out + i)[1] = o1;
}

extern "C" void kernel_launch(void* const* d_in, const int* in_sizes, int n_in,
                              void* d_out, int out_size, void* d_ws, size_t ws_size,
                              hipStream_t stream) {
  const float* mx   = (const float*)d_in[1];
  const int*   me_i = (const int*)d_in[2];
  const float* me_x = (const float*)d_in[3];
  const float* W1 = (const float*)d_in[8];
  const float* b1 = (const float*)d_in[9];
  const float* W2 = (const float*)d_in[10];
  const float* b2 = (const float*)d_in[11];
  const float* W3 = (const float*)d_in[12];
  const float* b3 = (const float*)d_in[13];
  const float* ln_w = (const float*)d_in[14];
  const float* ln_b = (const float*)d_in[15];

  // workspace layout (bytes, 256-aligned)
  char* ws = (char*)d_ws;
  u16* w1f = (u16*)(ws + 0);          // frag-layout W1 bf16 = 786432 B
  u16* w2t = (u16*)(ws + 786432);     // [64][512]  bf16 = 65536 B
  u16* w3t = (u16*)(ws + 851968);     // [256][64]  bf16 = 32768 B
  u16* mxb = (u16*)(ws + 884736);     // [MN][256]  bf16 = 20972544 B
  u16* h3  = (u16*)(ws + 21857280);   // [ME][256]  bf16 = 167761920 B
  float* partials = (float*)(ws + 189619200);  // NBLK*2*4 = 40960 B
  float* stats    = (float*)(ws + 189660160);  // 2 floats

  // output offsets: tuple order == input order, slot 3 replaced by me_x_new
  size_t off[8]; size_t a = 0;
  for (int i = 0; i < 8; ++i) { off[i] = a; a += (size_t)in_sizes[i]; }

  // pass-through: float arrays raw-copied; int index arrays converted to f32 VALUES
  for (int i = 0; i < 8; ++i) {
    if (i == 3) continue;
    if (i == 2 || i == 4 || i == 6) {
      int n = in_sizes[i];
      i2f_kernel<<<(n + 255) / 256, 256, 0, stream>>>(
          (const int*)d_in[i], (float*)d_out + off[i], n);
    } else {
      hipMemcpyAsync((char*)d_out + off[i] * 4, d_in[i], (size_t)in_sizes[i] * 4,
                     hipMemcpyDeviceToDevice, stream);
    }
  }

  // weight / input conversions
  wconv1_kernel<<<(512 * 768 + 255) / 256, 256, 0, stream>>>(W1, w1f);
  wconv_kernel<<<(512 * 64 + 255) / 256, 256, 0, stream>>>(W2, w2t, 512, 64);
  wconv_kernel<<<(64 * 256 + 255) / 256, 256, 0, stream>>>(W3, w3t, 64, 256);
  {
    int n = MN_N * MEMB_N;  // divisible by 8
    bfconv_kernel<<<(n / 8 + 255) / 256, 256, 0, stream>>>(mx, mxb, n);
  }

  gemm_fused_kernel<<<NBLK, 256, 0, stream>>>(mxb, me_i, me_x, w1f, b1, w2t, b2,
                                              w3t, b3, h3, partials);
  reduce_kernel<<<1, 256, 0, stream>>>(partials, NBLK, stats);

  const size_t total8 = (size_t)ME_N * EEMB_N / 8;
  final_kernel<<<(int)((total8 + 255) / 256), 256, 0, stream>>>(
      h3, me_x, ln_w, ln_b, stats, (float*)d_out + off[3]);
}